// Round 1
// baseline (216.406 us; speedup 1.0000x reference)
//
#include <hip/hip_runtime.h>

// SNN direction decoder — fused MFMA GEMM + LIF scan + FC2.
// B=256, T=100, I=512, H=1024, C=8.
// R6: K-loop rewritten. 32x32x16 f16 MFMA, block tile 128(t) x 256(h),
// 4 waves with 64x128 wave tiles (acc 2x4 x f32x16). Per 16-half chunk we
// stage {Ah, Al, Bh, Bl} ONCE (24 KB) and fire all 3 emulation products
// (xh*wh + xh*wl + xl*wh) from the same fragments -> 33% less staging and
// LDS-read traffic vs the old 3-segment loop, and the 64x128 wave tile
// halves reads/FLOP vs 64x64. Double-buffered LDS with counted
// s_waitcnt vmcnt(6) + raw s_barrier (T3/T4): stage loads stay in flight
// across barriers; vmcnt(0) only at the final chunk.
// LDS tile rows are 32 B pitch -> fragment b128 reads are naturally
// bank-uniform (8 hits/bank, minimum); gload_lds dest linear; no swizzle.
// fp32 GEMM emulated as 3-term f16 (inputs pre-scaled 2^6, un-scaled 2^-12).

#define B_   256
#define T_   100
#define I_   512
#define H_   1024
#define C_   8
#define M_   (B_ * T_)        // 25600
#define KS_  1024             // stored split width [hi|lo]
#define SC   64.0f            // 2^6 pre-scale
#define ISC  (1.0f / 4096.0f) // 2^-12 epilogue un-scale

typedef _Float16 half8 __attribute__((ext_vector_type(8)));
typedef float floatx16 __attribute__((ext_vector_type(16)));

__device__ __forceinline__ void ld_g2l(const _Float16* g, _Float16* l) {
    // async global->LDS, 16B/lane; LDS dest = wave-uniform base + lane*16
    __builtin_amdgcn_global_load_lds(
        (const __attribute__((address_space(1))) void*)g,
        (__attribute__((address_space(3))) void*)l, 16, 0, 0);
}

// Rows 0..25599: x -> Asp[row][hi|lo]; rows 25600..26623: W1 -> same buffer
// (Wsp region starts at Asp + 25600*1024). Blocks 0..7 also init logits.
__global__ void __launch_bounds__(256)
split_all(const float* __restrict__ x, const float* __restrict__ W1,
          const float* __restrict__ b2, _Float16* __restrict__ Asp,
          float* __restrict__ out) {
    int g = blockIdx.x * 256 + threadIdx.x;   // (M_+H_)*64 threads
    if (g < B_ * C_) out[g] = 100.0f * b2[g & (C_ - 1)];
    int row = g >> 6;
    int i0 = (g & 63) * 8;
    const float* src = (row < M_) ? (x + (size_t)row * I_ + i0)
                                  : (W1 + (size_t)(row - M_) * I_ + i0);
    float4 v0 = *(const float4*)(src);
    float4 v1 = *(const float4*)(src + 4);
    float vv[8] = {v0.x, v0.y, v0.z, v0.w, v1.x, v1.y, v1.z, v1.w};
    half8 hi, lo;
#pragma unroll
    for (int j = 0; j < 8; ++j) {
        float s = vv[j] * SC;
        _Float16 h = (_Float16)s;
        hi[j] = h;
        lo[j] = (_Float16)(s - (float)h);
    }
    _Float16* r = Asp + (size_t)row * KS_ + i0;
    *(half8*)(r) = hi;
    *(half8*)(r + 512) = lo;
}

#define MFMA32(A, Bv, Cacc) \
    Cacc = __builtin_amdgcn_mfma_f32_32x32x16_f16(A, Bv, Cacc, 0, 0, 0)

// One chunk = 16 k-halfs of each of {Ah, Al, Bh, Bl}.
// LDS buf layout (halfs): Ah[128*16] @0 | Al @2048 | Bh[256*16] @4096 | Bl @8192.
#define STAGE(dd, koff) do {                                         \
    _Float16* lb = &sm.buf[0][0] + (dd) * 12288;                     \
    ld_g2l(ga0 + (koff), lb + w * 512);                              \
    ld_g2l(ga1 + (koff), lb + 2048 + w * 512);                       \
    ld_g2l(gb00 + (koff), lb + 4096 + w * 1024);                     \
    ld_g2l(gb01 + (koff), lb + 4096 + w * 1024 + 512);               \
    ld_g2l(gb10 + (koff), lb + 8192 + w * 1024);                     \
    ld_g2l(gb11 + (koff), lb + 8192 + w * 1024 + 512);               \
} while (0)

#define COMPUTE(dd) do {                                             \
    const _Float16* bb = &sm.buf[0][0] + (dd) * 12288;               \
    half8 ah[2], al[2], bh[4], bl[4];                                \
    _Pragma("unroll")                                                \
    for (int f = 0; f < 2; ++f) {                                    \
        ah[f] = *(const half8*)(bb + ra + f * 512);                  \
        al[f] = *(const half8*)(bb + 2048 + ra + f * 512);           \
    }                                                                \
    _Pragma("unroll")                                                \
    for (int f = 0; f < 4; ++f) {                                    \
        bh[f] = *(const half8*)(bb + 4096 + rb + f * 512);           \
        bl[f] = *(const half8*)(bb + 8192 + rb + f * 512);           \
    }                                                                \
    _Pragma("unroll")                                                \
    for (int fm = 0; fm < 2; ++fm) {                                 \
        _Pragma("unroll")                                            \
        for (int fn = 0; fn < 4; ++fn) {                             \
            MFMA32(ah[fm], bh[fn], acc[fm][fn]);                     \
            MFMA32(ah[fm], bl[fn], acc[fm][fn]);                     \
            MFMA32(al[fm], bh[fn], acc[fm][fn]);                     \
        }                                                            \
    }                                                                \
} while (0)

// Fused: C-tile[t 0..127][256 h], then LIF scan + FC2. One batch per block,
// 4 h-tiles of 256. XCD-swizzled: xcd=blk&7 owns batches [32*xcd, 32*xcd+32).
// A rows 100..127 overread into next batch / Wsp (masked in scan).
__global__ void __launch_bounds__(256, 2)
snn_mfma(const _Float16* __restrict__ Asp, const _Float16* __restrict__ Wsp,
         const float* __restrict__ b1, const float* __restrict__ W2,
         float* __restrict__ logits) {
    __shared__ union {
        __align__(16) _Float16 buf[2][12288];  // double-buffered chunk
        float Cs[64 * 256];                    // epilogue staging
    } sm;
    const int tid = threadIdx.x;
    const int lane = tid & 63;
    const int w = tid >> 6;

    const int xcd = blockIdx.x & 7;
    const int jj = blockIdx.x >> 3;        // 0..127 per-XCD sequence
    const int b  = xcd * 32 + (jj >> 2);   // batch 0..255
    const int n0 = (jj & 3) * 256;         // h tile offset

    const int wm = (w >> 1) * 64;   // wave's 64x128 sub-tile
    const int wn = (w & 1) * 128;
    const int l31 = lane & 31;
    const int q2 = lane >> 5;

    // staging pointers: wave w stages A rows [32w,32w+32), B rows [64w,64w+64)
    const int rl = lane >> 1;
    const int cl8 = (lane & 1) * 8;
    const _Float16* ga0 = Asp + (size_t)(b * T_ + w * 32 + rl) * KS_ + cl8;
    const _Float16* ga1 = ga0 + 512;
    const _Float16* gb00 = Wsp + (size_t)(n0 + w * 64 + rl) * KS_ + cl8;
    const _Float16* gb01 = gb00 + 32 * KS_;
    const _Float16* gb10 = gb00 + 512;
    const _Float16* gb11 = gb01 + 512;

    // fragment LDS offsets (halfs) within a tile: row*16 + q2*8
    const int ra = (wm + l31) * 16 + q2 * 8;
    const int rb = (wn + l31) * 16 + q2 * 8;

    floatx16 acc[2][4];
#pragma unroll
    for (int i = 0; i < 2; ++i)
#pragma unroll
        for (int j = 0; j < 4; ++j)
#pragma unroll
            for (int e = 0; e < 16; ++e) acc[i][j][e] = 0.f;

    STAGE(0, 0);
#pragma unroll 2
    for (int c = 0; c < 31; ++c) {
        const int d = c & 1;
        STAGE(d ^ 1, (c + 1) * 16);
        asm volatile("s_waitcnt vmcnt(6)" ::: "memory");
        __builtin_amdgcn_s_barrier();
        COMPUTE(d);
        __builtin_amdgcn_s_barrier();
        asm volatile("" ::: "memory");
    }
    asm volatile("s_waitcnt vmcnt(0)" ::: "memory");
    __builtin_amdgcn_s_barrier();
    COMPUTE(1);
    __syncthreads();   // full fence: all ds reads/loads done before Cs overwrite

    // ---- epilogue: acc -> LDS (two 64-row phases) -> LIF scan + FC2 ----
    float b1c[4];
#pragma unroll
    for (int fn = 0; fn < 4; ++fn) b1c[fn] = b1[n0 + wn + fn * 32 + l31];

    float mem = 0.f, ss = 0.f;

    // phase A: waves 0,1 (wm=0) hold C rows 0..63 = t 0..63
    if (w < 2) {
#pragma unroll
        for (int fm = 0; fm < 2; ++fm)
#pragma unroll
            for (int r = 0; r < 16; ++r) {
                const int row = fm * 32 + (r & 3) + 8 * (r >> 2) + 4 * q2;
                float* dst = &sm.Cs[row * 256 + wn + l31];
#pragma unroll
                for (int fn = 0; fn < 4; ++fn)
                    dst[fn * 32] = acc[fm][fn][r] * ISC + b1c[fn];
            }
    }
    __syncthreads();
#pragma unroll 8
    for (int t = 0; t < 64; ++t) {
        float cv = sm.Cs[t * 256 + tid];
        float reset = (mem > 1.0f) ? 1.0f : 0.0f;
        mem = 0.9f * mem + cv - reset;
        ss += (mem > 1.0f) ? 1.0f : 0.0f;
    }
    __syncthreads();
    // phase B: waves 2,3 hold C rows 64..127; scan needs 64..99
    if (w >= 2) {
#pragma unroll
        for (int fm = 0; fm < 2; ++fm)
#pragma unroll
            for (int r = 0; r < 16; ++r) {
                const int row = fm * 32 + (r & 3) + 8 * (r >> 2) + 4 * q2;
                float* dst = &sm.Cs[row * 256 + wn + l31];
#pragma unroll
                for (int fn = 0; fn < 4; ++fn)
                    dst[fn * 32] = acc[fm][fn][r] * ISC + b1c[fn];
            }
    }
    __syncthreads();
#pragma unroll 6
    for (int t = 0; t < 36; ++t) {   // t global 64..99
        float cv = sm.Cs[t * 256 + tid];
        float reset = (mem > 1.0f) ? 1.0f : 0.0f;
        mem = 0.9f * mem + cv - reset;
        ss += (mem > 1.0f) ? 1.0f : 0.0f;
    }
    // ---- FC2: logits[b][c] += sum_h ss * W2[c][h] ----
#pragma unroll
    for (int cc = 0; cc < C_; ++cc) {
        float v = ss * W2[cc * H_ + n0 + tid];
#pragma unroll
        for (int off = 32; off; off >>= 1) v += __shfl_down(v, off, 64);
        if (lane == 0) atomicAdd(&logits[b * C_ + cc], v);
    }
}

extern "C" void kernel_launch(void* const* d_in, const int* in_sizes, int n_in,
                              void* d_out, int out_size, void* d_ws, size_t ws_size,
                              hipStream_t stream) {
    const float* x  = (const float*)d_in[0];
    const float* W1 = (const float*)d_in[1];
    const float* b1 = (const float*)d_in[2];
    const float* W2 = (const float*)d_in[3];
    const float* b2 = (const float*)d_in[4];
    float* out = (float*)d_out;

    // workspace: Asp [25600][1024] f16, Wsp [1024][1024] f16 directly after
    // (fused kernel's tail rows overread into Wsp by design).
    char* ws = (char*)d_ws;
    _Float16* Asp = (_Float16*)ws;
    _Float16* Wsp = (_Float16*)(ws + (size_t)M_ * KS_ * 2);

    hipLaunchKernelGGL(split_all, dim3((M_ + H_) * 64 / 256), dim3(256), 0, stream,
                       x, W1, b2, Asp, out);
    hipLaunchKernelGGL(snn_mfma, dim3(B_ * 4), dim3(256), 0, stream,
                       Asp, Wsp, b1, W2, out);
}